// Round 10
// baseline (313.066 us; speedup 1.0000x reference)
//
#include <hip/hip_runtime.h>
#include <math.h>

// ---------------- workspace layout (bytes) ----------------
// [0)            double sum
// [16)           unsigned minkey[64]
// [16+256)       unsigned maxkey[64]
// [16+512)       float u7[7]   (separable 1-D gaussian weights)

__device__ __forceinline__ unsigned fkey(float f) {
    unsigned u = __float_as_uint(f);
    return (u & 0x80000000u) ? ~u : (u | 0x80000000u);
}
__device__ __forceinline__ float funkey(unsigned k) {
    return __uint_as_float((k & 0x80000000u) ? (k & 0x7FFFFFFFu) : ~k);
}

__global__ void init_ws(const float* __restrict__ w, float* __restrict__ u7,
                        unsigned* __restrict__ mink, unsigned* __restrict__ maxk,
                        double* __restrict__ sum) {
    int t = threadIdx.x;
    if (t == 0) *sum = 0.0;
    if (t < 64) { mink[t] = 0xFFFFFFFFu; maxk[t] = 0u; }
    if (t < 7) {
        float s = 0.f;
        for (int j = 0; j < 7; ++j) s += w[t * 7 + j];
        u7[t] = s;  // row sums of normalized 2-D window == 1-D weights
    }
}

// per-batch min/max of Y. 16 blocks per batch, 256 threads, float4 loads.
__global__ __launch_bounds__(256) void minmax_kernel(const float4* __restrict__ Y,
                                                     unsigned* __restrict__ mink,
                                                     unsigned* __restrict__ maxk) {
    int b = blockIdx.x >> 4, ch = blockIdx.x & 15;
    const float4* p = Y + (size_t)b * 65536 + (size_t)ch * 4096 + threadIdx.x;
    float lmin = INFINITY, lmax = -INFINITY;
#pragma unroll
    for (int i = 0; i < 16; ++i) {
        float4 v = p[(size_t)i * 256];
        lmin = fminf(lmin, fminf(fminf(v.x, v.y), fminf(v.z, v.w)));
        lmax = fmaxf(lmax, fmaxf(fmaxf(v.x, v.y), fmaxf(v.z, v.w)));
    }
#pragma unroll
    for (int off = 32; off; off >>= 1) {
        lmin = fminf(lmin, __shfl_down(lmin, off));
        lmax = fmaxf(lmax, __shfl_down(lmax, off));
    }
    if ((threadIdx.x & 63) == 0) {
        atomicMin(&mink[b], fkey(lmin));
        atomicMax(&maxk[b], fkey(lmax));
    }
}

// ---------------------------------------------------------------------------
// Main SSIM kernel. r4 body verbatim (5-channel, mod-7 macro-literal ring,
// 2x14-step loop = proven 60 VGPR / no scratch / I$-safe), with ONE structural
// delta: LDS row buffers are PER-WAVE (each wave owns a 64-col strip + 6 halo
// entries), so all LDS communication is intra-wave. The DS pipe executes a
// wave's LDS ops in program order -> NO s_barrier / s_waitcnt needed; waves
// free-run and their LDS/VALU phases decorrelate (r4 was phase-locked by 38
// per-row barriers). Compiler reordering across the cross-lane halo hazard
// (per-thread alias analysis can't see it) is blocked by zero-cost
// asm volatile("" ::: "memory") fences around each ds_write.
// Tile: wave = 64 cols x 32 rows; block = 4 waves = 256 cols.
// Grid = 64 img * 2 colstrips * 16 rowstrips = 2048 blocks.
// ---------------------------------------------------------------------------
__global__ __launch_bounds__(256, 4) void ssim_kernel(const float* __restrict__ X,
                                                      const float* __restrict__ Yg,
                                                      const float* __restrict__ u7,
                                                      const unsigned* __restrict__ mink,
                                                      const unsigned* __restrict__ maxk,
                                                      double* __restrict__ sum) {
    __shared__ float2 s[4][2][72];     // [wave][buf][entry], entry e = col-c0+3
    __shared__ float warpsum[4];

    const int blk  = blockIdx.x;
    const int b    = blk >> 5;         // image
    const int sub  = blk & 31;
    const int cs   = sub & 1;          // col strip (0..1)
    const int rs   = sub >> 1;         // row strip (0..15)
    const int t    = threadIdx.x;
    const int wv   = t >> 6;           // wave id (0..3)
    const int lane = t & 63;
    const int c0   = (cs << 8) + (wv << 6);   // wave's first output col
    const int r0   = rs << 5;

    float2 (* __restrict__ sw)[72] = s[wv];   // this wave's two row buffers

    float u[7];
#pragma unroll
    for (int i = 0; i < 7; ++i) u[i] = u7[i];

    const float dr = funkey(maxk[b]) - funkey(mink[b]);
    float C1 = 0.01f * dr; C1 *= C1;
    float C2 = 0.03f * dr; C2 *= C2;
    const float cn = 49.f / 48.f;

    const float* __restrict__ Xb = X  + ((size_t)b << 18);
    const float* __restrict__ Yb = Yg + ((size_t)b << 18);

    const int  c    = c0 + lane;                  // main col, always in-image
    const bool hasE = (lane < 6);                 // halo entries 0..2, 67..69
    const int  eL   = (lane < 3) ? lane : (lane + 64);
    const int  ecol = c0 + eL - 3;
    const bool eok  = (ecol >= 0) && (ecol < 512);
    const int  ec   = min(max(ecol, 0), 511);

    float fx[2], fy[2], ex[2], ey[2];             // prefetch regs (row parity)
    float phx[7], phy[7], phxx[7], phyy[7], phxy[7];  // mod-7 ring
    float ssacc = 0.f;

// zero-runtime-cost compiler memory fence (pins DS op order; HW DS pipe is
// in-order per wave, so no s_waitcnt/s_barrier needed)
#define CBAR asm volatile("" ::: "memory")

#define LOADROW(P, JJ) do {                                                   \
    int r_ = r0 - 3 + (JJ);                                                   \
    if (r_ >= 0 && r_ < 512) {   /* block-uniform branch */                   \
        const float* xp_ = Xb + ((size_t)r_ << 9);                            \
        const float* yp_ = Yb + ((size_t)r_ << 9);                            \
        fx[(P)] = xp_[c]; fy[(P)] = yp_[c];                                   \
        if (hasE) { ex[(P)] = eok ? xp_[ec] : 0.f;                            \
                    ey[(P)] = eok ? yp_[ec] : 0.f; }                          \
    } else {                                                                  \
        fx[(P)] = 0.f; fy[(P)] = 0.f; ex[(P)] = 0.f; ey[(P)] = 0.f;           \
    }                                                                         \
} while (0)

#define WRITEROW(P) do {                                                      \
    CBAR;                                                                     \
    sw[(P)][lane + 3] = make_float2(fx[(P)], fy[(P)]);                        \
    if (hasE) sw[(P)][eL] = make_float2(ex[(P)], ey[(P)]);                    \
    CBAR;                                                                     \
} while (0)

#define HBLUR(BUF, SLOT) do {                                                 \
    float hx_ = 0.f, hy_ = 0.f, hxx_ = 0.f, hyy_ = 0.f, hxy_ = 0.f;           \
    _Pragma("unroll")                                                         \
    for (int k_ = 0; k_ < 7; ++k_) {                                          \
        float2 v_ = sw[(BUF)][lane + k_];                                     \
        float wx_ = u[k_] * v_.x, wy_ = u[k_] * v_.y;                         \
        hx_ += wx_; hy_ += wy_;                                               \
        hxx_ = fmaf(wx_, v_.x, hxx_);                                         \
        hxy_ = fmaf(wx_, v_.y, hxy_);                                         \
        hyy_ = fmaf(wy_, v_.y, hyy_);                                         \
    }                                                                         \
    phx[(SLOT)] = hx_; phy[(SLOT)] = hy_;                                     \
    phxx[(SLOT)] = hxx_; phyy[(SLOT)] = hyy_; phxy[(SLOT)] = hxy_;            \
} while (0)

// vertical blur: tap k reads slot (J+1+k)%7 with weight u[k]
#define VS(a, J) fmaf(u[6], a[(J) % 7], fmaf(u[5], a[((J)+6) % 7],            \
               fmaf(u[4], a[((J)+5) % 7], fmaf(u[3], a[((J)+4) % 7],          \
               fmaf(u[2], a[((J)+3) % 7], fmaf(u[1], a[((J)+2) % 7],          \
               u[0] * a[((J)+1) % 7]))))))

#define EMIT(J) do {                                                          \
    float mux = VS(phx, (J)), muy = VS(phy, (J));                             \
    float mxx = VS(phxx, (J)), myy = VS(phyy, (J)), mxy = VS(phxy, (J));      \
    float mux2 = mux * mux, muy2 = muy * muy, muxy = mux * muy;               \
    float sxx = (mxx - mux2) * cn;                                            \
    float syy = (myy - muy2) * cn;                                            \
    float sxy = (mxy - muxy) * cn;                                            \
    float num = (2.f * muxy + C1) * (2.f * sxy + C2);                         \
    float den = (mux2 + muy2 + C1) * (sxx + syy + C2);                        \
    ssacc = fmaf(num, __builtin_amdgcn_rcpf(den), ssacc);                     \
} while (0)

#define PSTEP(J) do {                                                         \
    HBLUR((J) & 1, (J) % 7);                                                  \
    WRITEROW(((J) + 1) & 1);                                                  \
    LOADROW(((J) + 1) & 1, (J) + 3);                                          \
} while (0)

#define MSTEP(J) do {                                                         \
    HBLUR((J) & 1, (J) % 7);                                                  \
    EMIT(J);                                                                  \
    WRITEROW(((J) + 1) & 1);                                                  \
    LOADROW(((J) + 1) & 1, jb + (J) + 3);                                     \
} while (0)

#define MSTEP_NL(J) do {                                                      \
    HBLUR((J) & 1, (J) % 7);                                                  \
    EMIT(J);                                                                  \
    WRITEROW(((J) + 1) & 1);                                                  \
} while (0)

#define MSTEP_END(J) do {                                                     \
    HBLUR((J) & 1, (J) % 7);                                                  \
    EMIT(J);                                                                  \
} while (0)

    // pre-prologue: rows 0,1 loaded; row 0 staged to buf0; row 2 in flight
    LOADROW(0, 0);
    LOADROW(1, 1);
    WRITEROW(0);
    LOADROW(0, 2);

    // prologue: rows 0..5 fill ring slots 0..5 (loads rows 3..8)
    PSTEP(0); PSTEP(1); PSTEP(2); PSTEP(3); PSTEP(4); PSTEP(5);

    // main: rows 6..33 (outputs 0..27); loads rows 9..36
    for (int g = 0; g < 2; ++g) {
        const int jb = 14 * g;
        MSTEP(6);  MSTEP(7);  MSTEP(8);  MSTEP(9);  MSTEP(10); MSTEP(11); MSTEP(12);
        MSTEP(13); MSTEP(14); MSTEP(15); MSTEP(16); MSTEP(17); MSTEP(18); MSTEP(19);
    }

    // tail: rows 34..37 (outputs 28..31)
    {
        const int jb = 28;
        MSTEP(6);        // row 34, loads row 37
        MSTEP_NL(7);     // row 35
        MSTEP_NL(8);     // row 36, stages row 37
        MSTEP_END(9);    // row 37
    }

#undef CBAR
#undef LOADROW
#undef WRITEROW
#undef HBLUR
#undef VS
#undef EMIT
#undef PSTEP
#undef MSTEP
#undef MSTEP_NL
#undef MSTEP_END

    // block reduction: wave shuffle -> LDS -> one double atomic per block
#pragma unroll
    for (int off = 32; off; off >>= 1) ssacc += __shfl_down(ssacc, off);
    if (lane == 0) warpsum[wv] = ssacc;
    __syncthreads();
    if (t == 0) {
        double sm = (double)warpsum[0] + (double)warpsum[1] +
                    (double)warpsum[2] + (double)warpsum[3];
        atomicAdd(sum, sm);
    }
}

__global__ void finalize_kernel(const double* __restrict__ sum, float* __restrict__ out) {
    out[0] = (float)(1.0 - (*sum) / (64.0 * 512.0 * 512.0));
}

extern "C" void kernel_launch(void* const* d_in, const int* in_sizes, int n_in,
                              void* d_out, int out_size, void* d_ws, size_t ws_size,
                              hipStream_t stream) {
    const float* X = (const float*)d_in[0];
    const float* Y = (const float*)d_in[1];
    const float* W = (const float*)d_in[2];

    char* ws = (char*)d_ws;
    double* sum = (double*)(ws + 0);
    unsigned* mink = (unsigned*)(ws + 16);
    unsigned* maxk = (unsigned*)(ws + 16 + 256);
    float* u7 = (float*)(ws + 16 + 512);

    init_ws<<<1, 64, 0, stream>>>(W, u7, mink, maxk, sum);
    minmax_kernel<<<1024, 256, 0, stream>>>((const float4*)Y, mink, maxk);
    ssim_kernel<<<2048, 256, 0, stream>>>(X, Y, u7, mink, maxk, sum);
    finalize_kernel<<<1, 1, 0, stream>>>(sum, (float*)d_out);
}